// Round 1
// baseline (599.738 us; speedup 1.0000x reference)
//
#include <hip/hip_runtime.h>
#include <hip/hip_bf16.h>

#define B_  8
#define NQ_ 2048
#define SK_ 2048
#define D_  128
#define QT  64          // Q rows per block (16 per wave)
#define KT  64          // K/V tile
#define NT  (SK_ / KT)  // 32 k-tiles

typedef __attribute__((ext_vector_type(8))) short bf16x8;
typedef __attribute__((ext_vector_type(4))) float f32x4;

// fp32 -> bf16 round-to-nearest-even
__device__ __forceinline__ unsigned short f2bf(float f) {
    union { float f; unsigned u; } v; v.f = f;
    unsigned r = v.u + 0x7fffu + ((v.u >> 16) & 1u);
    return (unsigned short)(r >> 16);
}

// Barrier that drains ONLY lgkm (LDS) — keeps global prefetch loads in flight.
// All cross-wave LDS data here is produced by ds_write from registers, so
// lgkmcnt(0) is the full producer-side requirement; vmcnt loads only feed
// registers and are consumer-waited by the compiler at their use sites.
__device__ __forceinline__ void wg_barrier() {
    asm volatile("s_waitcnt lgkmcnt(0)" ::: "memory");
    __builtin_amdgcn_s_barrier();
}

template<int KSPLIT>
__global__ __launch_bounds__(256, 4)
void sdpa_fwd(const float* __restrict__ Q, const float* __restrict__ K,
              const float* __restrict__ V, const int* __restrict__ M,
              const float* __restrict__ W, float* __restrict__ O,
              float* __restrict__ OP, float* __restrict__ MP,
              float* __restrict__ LP)
{
    const int b     = blockIdx.x & 7;               // batch -> XCD-local K/V reuse
    const int qbase = ((blockIdx.x >> 3) & 31) * QT;
    const int split = blockIdx.x >> 8;              // k-range owner
    constexpr int NTS = NT / KSPLIT;
    const int kt0   = split * NTS;

    // LDS budget 35840 B -> 4 blocks/CU. Ss is aliased on top of Ks (Ks is
    // dead after the QK reads; a mid-iteration barrier protects the overlap).
    __shared__ unsigned short Ks[KT][D_ + 8];   // 17408 B, K tile [k][d]
    __shared__ unsigned short Vt[D_][KT + 8];   // 18432 B, V tile transposed [d][k]
    unsigned short (*Ss)[KT + 8] = (unsigned short (*)[KT + 8])&Ks[0][0]; // 9216 B

    const int tid  = threadIdx.x;
    const int wv   = tid >> 6;
    const int lane = tid & 63;
    const int quad = lane >> 4;
    const int lq   = lane & 15;
    const int c4s  = (tid & 31) * 4;   // staging d-offset

    // ---- persistent Q A-fragments (wave rows wv*16 + lq), direct from global ----
    bf16x8 qf[4];
    {
        const float* qp = Q + ((size_t)b * NQ_ + qbase + wv * 16 + lq) * D_;
        #pragma unroll
        for (int t = 0; t < 4; ++t) {
            float4 a0 = *(const float4*)(qp + t * 32 + quad * 8);
            float4 a1 = *(const float4*)(qp + t * 32 + quad * 8 + 4);
            qf[t][0] = (short)f2bf(a0.x); qf[t][1] = (short)f2bf(a0.y);
            qf[t][2] = (short)f2bf(a0.z); qf[t][3] = (short)f2bf(a0.w);
            qf[t][4] = (short)f2bf(a1.x); qf[t][5] = (short)f2bf(a1.y);
            qf[t][6] = (short)f2bf(a1.z); qf[t][7] = (short)f2bf(a1.w);
        }
    }

    // online-softmax state in log2 domain; row = quad*4 + r of wave's 16 rows
    float m2[4], l[4];
    #pragma unroll
    for (int r = 0; r < 4; ++r) { m2[r] = -INFINITY; l[r] = 0.f; }
    f32x4 o[8];
    #pragma unroll
    for (int c = 0; c < 8; ++c) o[c] = (f32x4){0.f, 0.f, 0.f, 0.f};

    const float SCL = 0.08838834764831845f * 1.44269504088896f; // 1/sqrt(128)*log2e

    // W/mask prefetch registers (one tile ahead). Mask is int32.
    float    wr[4][4];
    unsigned mpack[4];
    const float* wp  = W + ((size_t)b * NQ_ + qbase + wv * 16 + quad * 4) * SK_ + lq;
    const int*   mp_ = M + ((size_t)b * NQ_ + qbase + wv * 16 + quad * 4) * SK_ + lq;
    auto load_wm = [&](int kb_el) {
        #pragma unroll
        for (int r = 0; r < 4; ++r) {
            unsigned mp = 0;
            #pragma unroll
            for (int c = 0; c < 4; ++c) {
                size_t idx = (size_t)r * SK_ + kb_el + c * 16;
                wr[r][c] = wp[idx];
                mp |= (mp_[idx] != 0 ? 1u : 0u) << c;
            }
            mpack[r] = mp;
        }
    };

    // K/V tile prefetch registers (one tile ahead)
    float4 kr[8], vr[8];
    auto load_kv = [&](int kb_el) {
        const float* kp = K + ((size_t)b * SK_ + kb_el) * D_ + c4s;
        const float* vp = V + ((size_t)b * SK_ + kb_el) * D_ + c4s;
        #pragma unroll
        for (int p = 0; p < 2; ++p) {
            int k4 = ((tid >> 5) + p * 8) * 4;
            #pragma unroll
            for (int i = 0; i < 4; ++i) {
                kr[p * 4 + i] = *(const float4*)(kp + (size_t)(k4 + i) * D_);
                vr[p * 4 + i] = *(const float4*)(vp + (size_t)(k4 + i) * D_);
            }
        }
    };

    load_kv(kt0 * KT);
    load_wm(kt0 * KT);

    #pragma unroll 1
    for (int kt = 0; kt < NTS; ++kt) {
        const int gt = kt0 + kt;
        // ---- stage prefetched K/V regs -> LDS (bf16; V transposed) ----
        #pragma unroll
        for (int p = 0; p < 2; ++p) {
            int k4 = ((tid >> 5) + p * 8) * 4;
            #pragma unroll
            for (int i = 0; i < 4; ++i) {
                float4 kv = kr[p * 4 + i];
                *(ushort4*)&Ks[k4 + i][c4s] =
                    make_ushort4(f2bf(kv.x), f2bf(kv.y), f2bf(kv.z), f2bf(kv.w));
            }
            float4 v0 = vr[p * 4 + 0], v1 = vr[p * 4 + 1];
            float4 v2 = vr[p * 4 + 2], v3 = vr[p * 4 + 3];
            // known ~16-way bank conflict on these writes; accepted this round
            *(ushort4*)&Vt[c4s + 0][k4] = make_ushort4(f2bf(v0.x), f2bf(v1.x), f2bf(v2.x), f2bf(v3.x));
            *(ushort4*)&Vt[c4s + 1][k4] = make_ushort4(f2bf(v0.y), f2bf(v1.y), f2bf(v2.y), f2bf(v3.y));
            *(ushort4*)&Vt[c4s + 2][k4] = make_ushort4(f2bf(v0.z), f2bf(v1.z), f2bf(v2.z), f2bf(v3.z));
            *(ushort4*)&Vt[c4s + 3][k4] = make_ushort4(f2bf(v0.w), f2bf(v1.w), f2bf(v2.w), f2bf(v3.w));
        }
        if (kt + 1 < NTS) load_kv((gt + 1) * KT);   // stays in flight across barriers
        wg_barrier();                               // stage visible to all waves

        // ---- S = Q Kt^T  (wave's 16 rows x 64 cols) ----
        f32x4 s[4];
        #pragma unroll
        for (int c = 0; c < 4; ++c) s[c] = (f32x4){0.f, 0.f, 0.f, 0.f};
        #pragma unroll
        for (int t = 0; t < 4; ++t) {
            #pragma unroll
            for (int c = 0; c < 4; ++c) {
                bf16x8 kf = *(const bf16x8*)&Ks[c * 16 + lq][t * 32 + quad * 8];
                s[c] = __builtin_amdgcn_mfma_f32_16x16x32_bf16(qf[t], kf, s[c], 0, 0, 0);
            }
        }

        // ---- logits (log2 domain): s * scale * w, mask -> -inf ----
        float lg[4][4];
        #pragma unroll
        for (int r = 0; r < 4; ++r)
            #pragma unroll
            for (int c = 0; c < 4; ++c) {
                float val = s[c][r] * (SCL * wr[r][c]);
                lg[r][c] = ((mpack[r] >> c) & 1u) ? -INFINITY : val;
            }
        if (kt + 1 < NTS) load_wm((gt + 1) * KT);   // prefetch next tile's W/mask

        wg_barrier();   // all waves done reading Ks -> Ss may overwrite it

        // ---- online softmax ----
        float alpha[4], p[4][4];
        #pragma unroll
        for (int r = 0; r < 4; ++r) {
            float tm = fmaxf(fmaxf(lg[r][0], lg[r][1]), fmaxf(lg[r][2], lg[r][3]));
            tm = fmaxf(tm, __shfl_xor(tm, 1));
            tm = fmaxf(tm, __shfl_xor(tm, 2));
            tm = fmaxf(tm, __shfl_xor(tm, 4));
            tm = fmaxf(tm, __shfl_xor(tm, 8));
            float mn = fmaxf(m2[r], tm);
            float ms = (mn == -INFINITY) ? 0.f : mn;   // all-masked guard
            float a  = exp2f(m2[r] - ms);
            alpha[r] = a;
            float rs = 0.f;
            #pragma unroll
            for (int c = 0; c < 4; ++c) {
                float pv = exp2f(lg[r][c] - ms);
                p[r][c] = pv;
                rs += pv;
            }
            rs += __shfl_xor(rs, 1);
            rs += __shfl_xor(rs, 2);
            rs += __shfl_xor(rs, 4);
            rs += __shfl_xor(rs, 8);
            l[r]  = l[r] * a + rs;
            m2[r] = mn;
        }
        #pragma unroll
        for (int c = 0; c < 8; ++c)
            #pragma unroll
            for (int r = 0; r < 4; ++r)
                o[c][r] *= alpha[r];

        // ---- P: C-layout -> LDS (aliased over Ks) -> A-layout; own wave's
        // rows only, same-wave LDS RAW is in-order ----
        #pragma unroll
        for (int r = 0; r < 4; ++r)
            #pragma unroll
            for (int c = 0; c < 4; ++c)
                Ss[wv * 16 + quad * 4 + r][c * 16 + lq] = f2bf(p[r][c]);

        // ---- O += P Vt ----
        #pragma unroll
        for (int t = 0; t < 2; ++t) {
            bf16x8 af = *(const bf16x8*)&Ss[wv * 16 + lq][t * 32 + quad * 8];
            #pragma unroll
            for (int c = 0; c < 8; ++c) {
                bf16x8 vf = *(const bf16x8*)&Vt[c * 16 + lq][t * 32 + quad * 8];
                o[c] = __builtin_amdgcn_mfma_f32_16x16x32_bf16(af, vf, o[c], 0, 0, 0);
            }
        }
        wg_barrier();   // protect Ks(Ss)/Vt before next stage
    }

    // ---- epilogue ----
    if (KSPLIT == 1) {
        #pragma unroll
        for (int r = 0; r < 4; ++r) {
            float li = 1.0f / l[r];
            float* op = O + ((size_t)b * NQ_ + qbase + wv * 16 + quad * 4 + r) * D_;
            #pragma unroll
            for (int c = 0; c < 8; ++c)
                op[c * 16 + lq] = o[c][r] * li;
        }
    } else {
        // unnormalized partial O + per-row (m, l) in log2 domain
        const size_t base = ((size_t)split * B_ + b) * NQ_ + qbase + wv * 16 + quad * 4;
        #pragma unroll
        for (int r = 0; r < 4; ++r) {
            float* op = OP + (base + r) * (size_t)D_;
            #pragma unroll
            for (int c = 0; c < 8; ++c)
                op[c * 16 + lq] = o[c][r];
            if (lq == 0) { MP[base + r] = m2[r]; LP[base + r] = l[r]; }
        }
    }
}

template<int KSPLIT>
__global__ __launch_bounds__(256)
void sdpa_merge(const float* __restrict__ OP, const float* __restrict__ MP,
                const float* __restrict__ LP, float* __restrict__ O)
{
    const int idx = blockIdx.x * 256 + threadIdx.x;   // over B*NQ*D/4
    const int row = idx >> 5;                         // D/4 = 32 float4 per row
    const int d4  = (idx & 31) * 4;
    constexpr size_t RN = (size_t)B_ * NQ_;

    float mr[KSPLIT];
    float m = -INFINITY;
    #pragma unroll
    for (int s = 0; s < KSPLIT; ++s) {
        mr[s] = MP[s * RN + row];
        m = fmaxf(m, mr[s]);
    }
    const float ms = (m == -INFINITY) ? 0.f : m;
    float L = 0.f;
    float4 acc = make_float4(0.f, 0.f, 0.f, 0.f);
    #pragma unroll
    for (int s = 0; s < KSPLIT; ++s) {
        const float a = exp2f(mr[s] - ms);            // exp2(-inf) = 0 for dead splits
        L += a * LP[s * RN + row];
        const float4 v = *(const float4*)(OP + (s * RN + row) * D_ + d4);
        acc.x += a * v.x; acc.y += a * v.y; acc.z += a * v.z; acc.w += a * v.w;
    }
    const float inv = 1.f / L;
    *(float4*)(O + (size_t)row * D_ + d4) =
        make_float4(acc.x * inv, acc.y * inv, acc.z * inv, acc.w * inv);
}

extern "C" void kernel_launch(void* const* d_in, const int* in_sizes, int n_in,
                              void* d_out, int out_size, void* d_ws, size_t ws_size,
                              hipStream_t stream) {
    const float* Q = (const float*)d_in[0];
    const float* K = (const float*)d_in[1];
    const float* V = (const float*)d_in[2];
    const int*   M = (const int*)d_in[3];    // bool mask uploaded as int32
    const float* W = (const float*)d_in[4];
    float*       O = (float*)d_out;

    const size_t RN = (size_t)B_ * NQ_;
    // per split: O partial (RN*D) + m (RN) + l (RN), all fp32
    auto need = [&](int s) { return (size_t)s * RN * (D_ + 2) * sizeof(float); };

    if (ws_size >= need(4)) {
        float* OP = (float*)d_ws;
        float* MP = OP + 4 * RN * D_;
        float* LP = MP + 4 * RN;
        sdpa_fwd<4><<<dim3(256 * 4), 256, 0, stream>>>(Q, K, V, M, W, O, OP, MP, LP);
        sdpa_merge<4><<<dim3((unsigned)(RN * D_ / 4 / 256)), 256, 0, stream>>>(OP, MP, LP, O);
    } else if (ws_size >= need(2)) {
        float* OP = (float*)d_ws;
        float* MP = OP + 2 * RN * D_;
        float* LP = MP + 2 * RN;
        sdpa_fwd<2><<<dim3(256 * 2), 256, 0, stream>>>(Q, K, V, M, W, O, OP, MP, LP);
        sdpa_merge<2><<<dim3((unsigned)(RN * D_ / 4 / 256)), 256, 0, stream>>>(OP, MP, LP, O);
    } else {
        sdpa_fwd<1><<<dim3(256), 256, 0, stream>>>(Q, K, V, M, W, O,
                                                   nullptr, nullptr, nullptr);
    }
}

// Round 2
// 507.513 us; speedup vs baseline: 1.1817x; 1.1817x over previous
//
#include <hip/hip_runtime.h>
#include <hip/hip_bf16.h>

#define B_  8
#define NQ_ 2048
#define SK_ 2048
#define D_  128
#define QT  64          // Q rows per block (16 per wave)
#define KT  64          // K/V tile
#define NT  (SK_ / KT)  // 32 k-tiles

typedef __attribute__((ext_vector_type(8))) short bf16x8;
typedef __attribute__((ext_vector_type(4))) float f32x4;

// fp32 -> bf16 round-to-nearest-even
__device__ __forceinline__ unsigned short f2bf(float f) {
    union { float f; unsigned u; } v; v.f = f;
    unsigned r = v.u + 0x7fffu + ((v.u >> 16) & 1u);
    return (unsigned short)(r >> 16);
}

// Barrier that drains ONLY lgkm (LDS) — keeps global prefetch loads in flight.
// All cross-wave LDS data here is produced by ds_write from registers, so
// lgkmcnt(0) is the full producer-side requirement; vmcnt loads only feed
// registers and are consumer-waited by the compiler at their use sites.
__device__ __forceinline__ void wg_barrier() {
    asm volatile("s_waitcnt lgkmcnt(0)" ::: "memory");
    __builtin_amdgcn_s_barrier();
}

template<int KSPLIT>
__global__ __launch_bounds__(256, 3)   // cap ~168 VGPR/wave: 3 blocks/CU, no spill
void sdpa_fwd(const float* __restrict__ Q, const float* __restrict__ K,
              const float* __restrict__ V, const int* __restrict__ M,
              const float* __restrict__ W, float* __restrict__ O,
              float* __restrict__ OP, float* __restrict__ MP,
              float* __restrict__ LP)
{
    const int b     = blockIdx.x & 7;               // batch -> XCD-local K/V reuse
    const int qbase = ((blockIdx.x >> 3) & 31) * QT;
    const int split = blockIdx.x >> 8;              // k-range owner
    constexpr int NTS = NT / KSPLIT;
    const int kt0   = split * NTS;

    // LDS budget 35840 B -> 3 blocks/CU (reg-limited). Ss aliases Ks (Ks is
    // dead after the QK reads; the mid-iteration barrier protects the overlap).
    __shared__ unsigned short Ks[KT][D_ + 8];   // 17408 B, K tile [k][d]
    __shared__ unsigned short Vt[D_][KT + 8];   // 18432 B, V tile transposed [d][k]
    unsigned short (*Ss)[KT + 8] = (unsigned short (*)[KT + 8])&Ks[0][0]; // 9216 B

    const int tid  = threadIdx.x;
    const int wv   = tid >> 6;
    const int lane = tid & 63;
    const int quad = lane >> 4;
    const int lq   = lane & 15;
    const int c4s  = (tid & 31) * 4;   // staging d-offset

    // ---- persistent Q A-fragments (wave rows wv*16 + lq), direct from global ----
    bf16x8 qf[4];
    {
        const float* qp = Q + ((size_t)b * NQ_ + qbase + wv * 16 + lq) * D_;
        #pragma unroll
        for (int t = 0; t < 4; ++t) {
            float4 a0 = *(const float4*)(qp + t * 32 + quad * 8);
            float4 a1 = *(const float4*)(qp + t * 32 + quad * 8 + 4);
            qf[t][0] = (short)f2bf(a0.x); qf[t][1] = (short)f2bf(a0.y);
            qf[t][2] = (short)f2bf(a0.z); qf[t][3] = (short)f2bf(a0.w);
            qf[t][4] = (short)f2bf(a1.x); qf[t][5] = (short)f2bf(a1.y);
            qf[t][6] = (short)f2bf(a1.z); qf[t][7] = (short)f2bf(a1.w);
        }
    }

    // online-softmax state in log2 domain; row = quad*4 + r of wave's 16 rows
    float m2[4], l[4];
    #pragma unroll
    for (int r = 0; r < 4; ++r) { m2[r] = -INFINITY; l[r] = 0.f; }
    f32x4 o[8];
    #pragma unroll
    for (int c = 0; c < 8; ++c) o[c] = (f32x4){0.f, 0.f, 0.f, 0.f};

    const float SCL = 0.08838834764831845f * 1.44269504088896f; // 1/sqrt(128)*log2e

    // W/mask prefetch registers (one tile ahead). Mask is int32.
    float    wr[4][4];
    unsigned mpack[4];
    const float* wp  = W + ((size_t)b * NQ_ + qbase + wv * 16 + quad * 4) * SK_ + lq;
    const int*   mp_ = M + ((size_t)b * NQ_ + qbase + wv * 16 + quad * 4) * SK_ + lq;
    auto load_wm = [&](int kb_el) {
        #pragma unroll
        for (int r = 0; r < 4; ++r) {
            unsigned mp = 0;
            #pragma unroll
            for (int c = 0; c < 4; ++c) {
                size_t idx = (size_t)r * SK_ + kb_el + c * 16;
                wr[r][c] = wp[idx];
                mp |= (mp_[idx] != 0 ? 1u : 0u) << c;
            }
            mpack[r] = mp;
        }
    };

    // K/V tile prefetch registers (one tile ahead)
    float4 kr[8], vr[8];
    auto load_kv = [&](int kb_el) {
        const float* kp = K + ((size_t)b * SK_ + kb_el) * D_ + c4s;
        const float* vp = V + ((size_t)b * SK_ + kb_el) * D_ + c4s;
        #pragma unroll
        for (int p = 0; p < 2; ++p) {
            int k4 = ((tid >> 5) + p * 8) * 4;
            #pragma unroll
            for (int i = 0; i < 4; ++i) {
                kr[p * 4 + i] = *(const float4*)(kp + (size_t)(k4 + i) * D_);
                vr[p * 4 + i] = *(const float4*)(vp + (size_t)(k4 + i) * D_);
            }
        }
    };

    load_kv(kt0 * KT);
    load_wm(kt0 * KT);

    #pragma unroll 1
    for (int kt = 0; kt < NTS; ++kt) {
        const int gt = kt0 + kt;
        // ---- stage prefetched K/V regs -> LDS (bf16; V transposed) ----
        #pragma unroll
        for (int p = 0; p < 2; ++p) {
            int k4 = ((tid >> 5) + p * 8) * 4;
            #pragma unroll
            for (int i = 0; i < 4; ++i) {
                float4 kv = kr[p * 4 + i];
                *(ushort4*)&Ks[k4 + i][c4s] =
                    make_ushort4(f2bf(kv.x), f2bf(kv.y), f2bf(kv.z), f2bf(kv.w));
            }
            float4 v0 = vr[p * 4 + 0], v1 = vr[p * 4 + 1];
            float4 v2 = vr[p * 4 + 2], v3 = vr[p * 4 + 3];
            // known ~16-way bank conflict on these writes; accepted this round
            *(ushort4*)&Vt[c4s + 0][k4] = make_ushort4(f2bf(v0.x), f2bf(v1.x), f2bf(v2.x), f2bf(v3.x));
            *(ushort4*)&Vt[c4s + 1][k4] = make_ushort4(f2bf(v0.y), f2bf(v1.y), f2bf(v2.y), f2bf(v3.y));
            *(ushort4*)&Vt[c4s + 2][k4] = make_ushort4(f2bf(v0.z), f2bf(v1.z), f2bf(v2.z), f2bf(v3.z));
            *(ushort4*)&Vt[c4s + 3][k4] = make_ushort4(f2bf(v0.w), f2bf(v1.w), f2bf(v2.w), f2bf(v3.w));
        }
        if (kt + 1 < NTS) load_kv((gt + 1) * KT);   // stays in flight across barriers
        wg_barrier();                               // stage visible to all waves

        // ---- S = Q Kt^T  (wave's 16 rows x 64 cols) ----
        f32x4 s[4];
        #pragma unroll
        for (int c = 0; c < 4; ++c) s[c] = (f32x4){0.f, 0.f, 0.f, 0.f};
        #pragma unroll
        for (int t = 0; t < 4; ++t) {
            #pragma unroll
            for (int c = 0; c < 4; ++c) {
                bf16x8 kf = *(const bf16x8*)&Ks[c * 16 + lq][t * 32 + quad * 8];
                s[c] = __builtin_amdgcn_mfma_f32_16x16x32_bf16(qf[t], kf, s[c], 0, 0, 0);
            }
        }

        // ---- logits IN PLACE (log2 domain): s = s*scale*w, mask -> -inf ----
        #pragma unroll
        for (int r = 0; r < 4; ++r)
            #pragma unroll
            for (int c = 0; c < 4; ++c) {
                float val = s[c][r] * (SCL * wr[r][c]);
                s[c][r] = ((mpack[r] >> c) & 1u) ? -INFINITY : val;
            }
        if (kt + 1 < NTS) load_wm((gt + 1) * KT);   // prefetch next tile's W/mask

        wg_barrier();   // all waves done reading Ks -> Ss may overwrite it

        // ---- online softmax (P stored to Ss inside the exp loop) ----
        float alpha[4];
        #pragma unroll
        for (int r = 0; r < 4; ++r) {
            float tm = fmaxf(fmaxf(s[0][r], s[1][r]), fmaxf(s[2][r], s[3][r]));
            tm = fmaxf(tm, __shfl_xor(tm, 1));
            tm = fmaxf(tm, __shfl_xor(tm, 2));
            tm = fmaxf(tm, __shfl_xor(tm, 4));
            tm = fmaxf(tm, __shfl_xor(tm, 8));
            float mn = fmaxf(m2[r], tm);
            float ms = (mn == -INFINITY) ? 0.f : mn;   // all-masked guard
            alpha[r] = exp2f(m2[r] - ms);
            float rs = 0.f;
            #pragma unroll
            for (int c = 0; c < 4; ++c) {
                float pv = exp2f(s[c][r] - ms);
                rs += pv;
                Ss[wv * 16 + quad * 4 + r][c * 16 + lq] = f2bf(pv);
            }
            rs += __shfl_xor(rs, 1);
            rs += __shfl_xor(rs, 2);
            rs += __shfl_xor(rs, 4);
            rs += __shfl_xor(rs, 8);
            l[r]  = l[r] * alpha[r] + rs;
            m2[r] = mn;
        }
        #pragma unroll
        for (int c = 0; c < 8; ++c)
            #pragma unroll
            for (int r = 0; r < 4; ++r)
                o[c][r] *= alpha[r];

        // ---- O += P Vt  (same-wave LDS RAW on Ss is in-order, no barrier) ----
        #pragma unroll
        for (int t = 0; t < 2; ++t) {
            bf16x8 af = *(const bf16x8*)&Ss[wv * 16 + lq][t * 32 + quad * 8];
            #pragma unroll
            for (int c = 0; c < 8; ++c) {
                bf16x8 vf = *(const bf16x8*)&Vt[c * 16 + lq][t * 32 + quad * 8];
                o[c] = __builtin_amdgcn_mfma_f32_16x16x32_bf16(af, vf, o[c], 0, 0, 0);
            }
        }
        wg_barrier();   // protect Ks(Ss)/Vt before next stage
    }

    // ---- epilogue ----
    if (KSPLIT == 1) {
        #pragma unroll
        for (int r = 0; r < 4; ++r) {
            float li = 1.0f / l[r];
            float* op = O + ((size_t)b * NQ_ + qbase + wv * 16 + quad * 4 + r) * D_;
            #pragma unroll
            for (int c = 0; c < 8; ++c)
                op[c * 16 + lq] = o[c][r] * li;
        }
    } else {
        // unnormalized partial O + per-row (m, l) in log2 domain
        const size_t base = ((size_t)split * B_ + b) * NQ_ + qbase + wv * 16 + quad * 4;
        #pragma unroll
        for (int r = 0; r < 4; ++r) {
            float* op = OP + (base + r) * (size_t)D_;
            #pragma unroll
            for (int c = 0; c < 8; ++c)
                op[c * 16 + lq] = o[c][r];
            if (lq == 0) { MP[base + r] = m2[r]; LP[base + r] = l[r]; }
        }
    }
}

template<int KSPLIT>
__global__ __launch_bounds__(256)
void sdpa_merge(const float* __restrict__ OP, const float* __restrict__ MP,
                const float* __restrict__ LP, float* __restrict__ O)
{
    const int idx = blockIdx.x * 256 + threadIdx.x;   // over B*NQ*D/4
    const int row = idx >> 5;                         // D/4 = 32 float4 per row
    const int d4  = (idx & 31) * 4;
    constexpr size_t RN = (size_t)B_ * NQ_;

    float mr[KSPLIT];
    float m = -INFINITY;
    #pragma unroll
    for (int s = 0; s < KSPLIT; ++s) {
        mr[s] = MP[s * RN + row];
        m = fmaxf(m, mr[s]);
    }
    const float ms = (m == -INFINITY) ? 0.f : m;
    float L = 0.f;
    float4 acc = make_float4(0.f, 0.f, 0.f, 0.f);
    #pragma unroll
    for (int s = 0; s < KSPLIT; ++s) {
        const float a = exp2f(mr[s] - ms);            // exp2(-inf) = 0 for dead splits
        L += a * LP[s * RN + row];
        const float4 v = *(const float4*)(OP + (s * RN + row) * D_ + d4);
        acc.x += a * v.x; acc.y += a * v.y; acc.z += a * v.z; acc.w += a * v.w;
    }
    const float inv = 1.f / L;
    *(float4*)(O + (size_t)row * D_ + d4) =
        make_float4(acc.x * inv, acc.y * inv, acc.z * inv, acc.w * inv);
}

extern "C" void kernel_launch(void* const* d_in, const int* in_sizes, int n_in,
                              void* d_out, int out_size, void* d_ws, size_t ws_size,
                              hipStream_t stream) {
    const float* Q = (const float*)d_in[0];
    const float* K = (const float*)d_in[1];
    const float* V = (const float*)d_in[2];
    const int*   M = (const int*)d_in[3];    // bool mask uploaded as int32
    const float* W = (const float*)d_in[4];
    float*       O = (float*)d_out;

    const size_t RN = (size_t)B_ * NQ_;
    // per split: O partial (RN*D) + m (RN) + l (RN), all fp32
    auto need = [&](int s) { return (size_t)s * RN * (D_ + 2) * sizeof(float); };

    if (ws_size >= need(4)) {
        float* OP = (float*)d_ws;
        float* MP = OP + 4 * RN * D_;
        float* LP = MP + 4 * RN;
        sdpa_fwd<4><<<dim3(256 * 4), 256, 0, stream>>>(Q, K, V, M, W, O, OP, MP, LP);
        sdpa_merge<4><<<dim3((unsigned)(RN * D_ / 4 / 256)), 256, 0, stream>>>(OP, MP, LP, O);
    } else if (ws_size >= need(2)) {
        float* OP = (float*)d_ws;
        float* MP = OP + 2 * RN * D_;
        float* LP = MP + 2 * RN;
        sdpa_fwd<2><<<dim3(256 * 2), 256, 0, stream>>>(Q, K, V, M, W, O, OP, MP, LP);
        sdpa_merge<2><<<dim3((unsigned)(RN * D_ / 4 / 256)), 256, 0, stream>>>(OP, MP, LP, O);
    } else {
        sdpa_fwd<1><<<dim3(256), 256, 0, stream>>>(Q, K, V, M, W, O,
                                                   nullptr, nullptr, nullptr);
    }
}

// Round 3
// 335.932 us; speedup vs baseline: 1.7853x; 1.5108x over previous
//
#include <hip/hip_runtime.h>
#include <hip/hip_bf16.h>

#define B_  8
#define NQ_ 2048
#define SK_ 2048
#define D_  128
#define QT  64          // Q rows per block (16 per wave)
#define KT  64          // K/V tile
#define NT  (SK_ / KT)  // 32 k-tiles

typedef __attribute__((ext_vector_type(8))) short bf16x8;
typedef __attribute__((ext_vector_type(4))) float f32x4;

// fp32 -> bf16 round-to-nearest-even
__device__ __forceinline__ unsigned short f2bf(float f) {
    union { float f; unsigned u; } v; v.f = f;
    unsigned r = v.u + 0x7fffu + ((v.u >> 16) & 1u);
    return (unsigned short)(r >> 16);
}

// Barrier that drains ONLY lgkm (LDS) — keeps global prefetch loads in flight.
// All cross-wave LDS data here is produced by ds_write from registers, so
// lgkmcnt(0) is the full producer-side requirement; vmcnt loads only feed
// registers and are consumer-waited by the compiler at their use sites.
__device__ __forceinline__ void wg_barrier() {
    asm volatile("s_waitcnt lgkmcnt(0)" ::: "memory");
    __builtin_amdgcn_s_barrier();
}

// (256,2): VGPR cap 256/wave — round-0 codegen (120 arch VGPR, zero scratch)
// fits with slack. (256,3)/(256,4) forced a <=128 unified cap -> arch-VGPR
// squeeze -> 115+ MB of spill traffic per dispatch (measured rounds 1-2).
template<int KSPLIT>
__global__ __launch_bounds__(256, 2)
void sdpa_fwd(const float* __restrict__ Q, const float* __restrict__ K,
              const float* __restrict__ V, const int* __restrict__ M,
              const float* __restrict__ W, float* __restrict__ O,
              float* __restrict__ OP, float* __restrict__ MP,
              float* __restrict__ LP)
{
    const int b     = blockIdx.x & 7;               // batch -> XCD-local K/V reuse
    const int qbase = ((blockIdx.x >> 3) & 31) * QT;
    const int split = blockIdx.x >> 8;              // k-range owner
    constexpr int NTS = NT / KSPLIT;
    const int kt0   = split * NTS;

    // Ss aliases Ks (Ks is dead after the QK reads; the mid-iteration barrier
    // protects the overlap). 35840 B total.
    __shared__ unsigned short Ks[KT][D_ + 8];   // 17408 B, K tile [k][d]
    __shared__ unsigned short Vt[D_][KT + 8];   // 18432 B, V tile transposed [d][k]
    unsigned short (*Ss)[KT + 8] = (unsigned short (*)[KT + 8])&Ks[0][0]; // 9216 B

    const int tid  = threadIdx.x;
    const int wv   = tid >> 6;
    const int lane = tid & 63;
    const int quad = lane >> 4;
    const int lq   = lane & 15;
    const int c4s  = (tid & 31) * 4;   // staging d-offset

    // ---- persistent Q A-fragments (wave rows wv*16 + lq), direct from global ----
    bf16x8 qf[4];
    {
        const float* qp = Q + ((size_t)b * NQ_ + qbase + wv * 16 + lq) * D_;
        #pragma unroll
        for (int t = 0; t < 4; ++t) {
            float4 a0 = *(const float4*)(qp + t * 32 + quad * 8);
            float4 a1 = *(const float4*)(qp + t * 32 + quad * 8 + 4);
            qf[t][0] = (short)f2bf(a0.x); qf[t][1] = (short)f2bf(a0.y);
            qf[t][2] = (short)f2bf(a0.z); qf[t][3] = (short)f2bf(a0.w);
            qf[t][4] = (short)f2bf(a1.x); qf[t][5] = (short)f2bf(a1.y);
            qf[t][6] = (short)f2bf(a1.z); qf[t][7] = (short)f2bf(a1.w);
        }
    }

    // online-softmax state in log2 domain; row = quad*4 + r of wave's 16 rows
    float m2[4], l[4];
    #pragma unroll
    for (int r = 0; r < 4; ++r) { m2[r] = -INFINITY; l[r] = 0.f; }
    f32x4 o[8];
    #pragma unroll
    for (int c = 0; c < 8; ++c) o[c] = (f32x4){0.f, 0.f, 0.f, 0.f};

    const float SCL = 0.08838834764831845f * 1.44269504088896f; // 1/sqrt(128)*log2e

    // W/mask prefetch registers (one tile ahead). Mask is int32.
    float    wr[4][4];
    unsigned mpack[4];
    const float* wp  = W + ((size_t)b * NQ_ + qbase + wv * 16 + quad * 4) * SK_ + lq;
    const int*   mp_ = M + ((size_t)b * NQ_ + qbase + wv * 16 + quad * 4) * SK_ + lq;
    auto load_wm = [&](int kb_el) {
        #pragma unroll
        for (int r = 0; r < 4; ++r) {
            unsigned mp = 0;
            #pragma unroll
            for (int c = 0; c < 4; ++c) {
                size_t idx = (size_t)r * SK_ + kb_el + c * 16;
                wr[r][c] = wp[idx];
                mp |= (mp_[idx] != 0 ? 1u : 0u) << c;
            }
            mpack[r] = mp;
        }
    };

    // K/V tile prefetch registers (one tile ahead)
    float4 kr[8], vr[8];
    auto load_kv = [&](int kb_el) {
        const float* kp = K + ((size_t)b * SK_ + kb_el) * D_ + c4s;
        const float* vp = V + ((size_t)b * SK_ + kb_el) * D_ + c4s;
        #pragma unroll
        for (int p = 0; p < 2; ++p) {
            int k4 = ((tid >> 5) + p * 8) * 4;
            #pragma unroll
            for (int i = 0; i < 4; ++i) {
                kr[p * 4 + i] = *(const float4*)(kp + (size_t)(k4 + i) * D_);
                vr[p * 4 + i] = *(const float4*)(vp + (size_t)(k4 + i) * D_);
            }
        }
    };

    load_kv(kt0 * KT);
    load_wm(kt0 * KT);

    #pragma unroll 1
    for (int kt = 0; kt < NTS; ++kt) {
        const int gt = kt0 + kt;
        // ---- stage prefetched K/V regs -> LDS (bf16; V transposed) ----
        #pragma unroll
        for (int p = 0; p < 2; ++p) {
            int k4 = ((tid >> 5) + p * 8) * 4;
            #pragma unroll
            for (int i = 0; i < 4; ++i) {
                float4 kv = kr[p * 4 + i];
                *(ushort4*)&Ks[k4 + i][c4s] =
                    make_ushort4(f2bf(kv.x), f2bf(kv.y), f2bf(kv.z), f2bf(kv.w));
            }
            float4 v0 = vr[p * 4 + 0], v1 = vr[p * 4 + 1];
            float4 v2 = vr[p * 4 + 2], v3 = vr[p * 4 + 3];
            // known ~16-way bank conflict on these writes; next-round target
            *(ushort4*)&Vt[c4s + 0][k4] = make_ushort4(f2bf(v0.x), f2bf(v1.x), f2bf(v2.x), f2bf(v3.x));
            *(ushort4*)&Vt[c4s + 1][k4] = make_ushort4(f2bf(v0.y), f2bf(v1.y), f2bf(v2.y), f2bf(v3.y));
            *(ushort4*)&Vt[c4s + 2][k4] = make_ushort4(f2bf(v0.z), f2bf(v1.z), f2bf(v2.z), f2bf(v3.z));
            *(ushort4*)&Vt[c4s + 3][k4] = make_ushort4(f2bf(v0.w), f2bf(v1.w), f2bf(v2.w), f2bf(v3.w));
        }
        if (kt + 1 < NTS) load_kv((gt + 1) * KT);   // stays in flight across barriers
        wg_barrier();                               // stage visible to all waves

        // ---- S = Q Kt^T  (wave's 16 rows x 64 cols) ----
        f32x4 s[4];
        #pragma unroll
        for (int c = 0; c < 4; ++c) s[c] = (f32x4){0.f, 0.f, 0.f, 0.f};
        #pragma unroll
        for (int t = 0; t < 4; ++t) {
            #pragma unroll
            for (int c = 0; c < 4; ++c) {
                bf16x8 kf = *(const bf16x8*)&Ks[c * 16 + lq][t * 32 + quad * 8];
                s[c] = __builtin_amdgcn_mfma_f32_16x16x32_bf16(qf[t], kf, s[c], 0, 0, 0);
            }
        }

        // ---- logits IN PLACE (log2 domain): s = s*scale*w, mask -> -inf ----
        #pragma unroll
        for (int r = 0; r < 4; ++r)
            #pragma unroll
            for (int c = 0; c < 4; ++c) {
                float val = s[c][r] * (SCL * wr[r][c]);
                s[c][r] = ((mpack[r] >> c) & 1u) ? -INFINITY : val;
            }
        if (kt + 1 < NTS) load_wm((gt + 1) * KT);   // prefetch next tile's W/mask

        wg_barrier();   // all waves done reading Ks -> Ss may overwrite it

        // ---- online softmax (P stored to Ss inside the exp loop) ----
        float alpha[4];
        #pragma unroll
        for (int r = 0; r < 4; ++r) {
            float tm = fmaxf(fmaxf(s[0][r], s[1][r]), fmaxf(s[2][r], s[3][r]));
            tm = fmaxf(tm, __shfl_xor(tm, 1));
            tm = fmaxf(tm, __shfl_xor(tm, 2));
            tm = fmaxf(tm, __shfl_xor(tm, 4));
            tm = fmaxf(tm, __shfl_xor(tm, 8));
            float mn = fmaxf(m2[r], tm);
            float ms = (mn == -INFINITY) ? 0.f : mn;   // all-masked guard
            alpha[r] = exp2f(m2[r] - ms);
            float rs = 0.f;
            #pragma unroll
            for (int c = 0; c < 4; ++c) {
                float pv = exp2f(s[c][r] - ms);
                rs += pv;
                Ss[wv * 16 + quad * 4 + r][c * 16 + lq] = f2bf(pv);
            }
            rs += __shfl_xor(rs, 1);
            rs += __shfl_xor(rs, 2);
            rs += __shfl_xor(rs, 4);
            rs += __shfl_xor(rs, 8);
            l[r]  = l[r] * alpha[r] + rs;
            m2[r] = mn;
        }
        #pragma unroll
        for (int c = 0; c < 8; ++c)
            #pragma unroll
            for (int r = 0; r < 4; ++r)
                o[c][r] *= alpha[r];

        // ---- O += P Vt  (same-wave LDS RAW on Ss is in-order, no barrier) ----
        #pragma unroll
        for (int t = 0; t < 2; ++t) {
            bf16x8 af = *(const bf16x8*)&Ss[wv * 16 + lq][t * 32 + quad * 8];
            #pragma unroll
            for (int c = 0; c < 8; ++c) {
                bf16x8 vf = *(const bf16x8*)&Vt[c * 16 + lq][t * 32 + quad * 8];
                o[c] = __builtin_amdgcn_mfma_f32_16x16x32_bf16(af, vf, o[c], 0, 0, 0);
            }
        }
        wg_barrier();   // protect Ks(Ss)/Vt before next stage
    }

    // ---- epilogue ----
    if (KSPLIT == 1) {
        #pragma unroll
        for (int r = 0; r < 4; ++r) {
            float li = 1.0f / l[r];
            float* op = O + ((size_t)b * NQ_ + qbase + wv * 16 + quad * 4 + r) * D_;
            #pragma unroll
            for (int c = 0; c < 8; ++c)
                op[c * 16 + lq] = o[c][r] * li;
        }
    } else {
        // unnormalized partial O + per-row (m, l) in log2 domain
        const size_t base = ((size_t)split * B_ + b) * NQ_ + qbase + wv * 16 + quad * 4;
        #pragma unroll
        for (int r = 0; r < 4; ++r) {
            float* op = OP + (base + r) * (size_t)D_;
            #pragma unroll
            for (int c = 0; c < 8; ++c)
                op[c * 16 + lq] = o[c][r];
            if (lq == 0) { MP[base + r] = m2[r]; LP[base + r] = l[r]; }
        }
    }
}

template<int KSPLIT>
__global__ __launch_bounds__(256)
void sdpa_merge(const float* __restrict__ OP, const float* __restrict__ MP,
                const float* __restrict__ LP, float* __restrict__ O)
{
    const int idx = blockIdx.x * 256 + threadIdx.x;   // over B*NQ*D/4
    const int row = idx >> 5;                         // D/4 = 32 float4 per row
    const int d4  = (idx & 31) * 4;
    constexpr size_t RN = (size_t)B_ * NQ_;

    float mr[KSPLIT];
    float m = -INFINITY;
    #pragma unroll
    for (int s = 0; s < KSPLIT; ++s) {
        mr[s] = MP[s * RN + row];
        m = fmaxf(m, mr[s]);
    }
    const float ms = (m == -INFINITY) ? 0.f : m;
    float L = 0.f;
    float4 acc = make_float4(0.f, 0.f, 0.f, 0.f);
    #pragma unroll
    for (int s = 0; s < KSPLIT; ++s) {
        const float a = exp2f(mr[s] - ms);            // exp2(-inf) = 0 for dead splits
        L += a * LP[s * RN + row];
        const float4 v = *(const float4*)(OP + (s * RN + row) * D_ + d4);
        acc.x += a * v.x; acc.y += a * v.y; acc.z += a * v.z; acc.w += a * v.w;
    }
    const float inv = 1.f / L;
    *(float4*)(O + (size_t)row * D_ + d4) =
        make_float4(acc.x * inv, acc.y * inv, acc.z * inv, acc.w * inv);
}

extern "C" void kernel_launch(void* const* d_in, const int* in_sizes, int n_in,
                              void* d_out, int out_size, void* d_ws, size_t ws_size,
                              hipStream_t stream) {
    const float* Q = (const float*)d_in[0];
    const float* K = (const float*)d_in[1];
    const float* V = (const float*)d_in[2];
    const int*   M = (const int*)d_in[3];    // bool mask uploaded as int32
    const float* W = (const float*)d_in[4];
    float*       O = (float*)d_out;

    const size_t RN = (size_t)B_ * NQ_;
    // per split: O partial (RN*D) + m (RN) + l (RN), all fp32
    auto need = [&](int s) { return (size_t)s * RN * (D_ + 2) * sizeof(float); };

    if (ws_size >= need(2)) {
        // KSPLIT=2: 512 blocks = one full pass at 2 blocks/CU; half the
        // partial-O round-trip of KSPLIT=4, same waves/SIMD concurrency.
        float* OP = (float*)d_ws;
        float* MP = OP + 2 * RN * D_;
        float* LP = MP + 2 * RN;
        sdpa_fwd<2><<<dim3(256 * 2), 256, 0, stream>>>(Q, K, V, M, W, O, OP, MP, LP);
        sdpa_merge<2><<<dim3((unsigned)(RN * D_ / 4 / 256)), 256, 0, stream>>>(OP, MP, LP, O);
    } else {
        sdpa_fwd<1><<<dim3(256), 256, 0, stream>>>(Q, K, V, M, W, O,
                                                   nullptr, nullptr, nullptr);
    }
}

// Round 6
// 329.458 us; speedup vs baseline: 1.8204x; 1.0196x over previous
//
#include <hip/hip_runtime.h>
#include <hip/hip_bf16.h>

#define B_  8
#define NQ_ 2048
#define SK_ 2048
#define D_  128
#define QT  64          // Q rows per block (16 per wave)
#define KT  32          // K/V tile (halved vs r3: halves staging regs -> fits (256,3))
#define NT  (SK_ / KT)  // 64 k-tiles

typedef __attribute__((ext_vector_type(8))) short bf16x8;
typedef __attribute__((ext_vector_type(4))) float f32x4;
typedef unsigned short u16;

// fp32 -> bf16 round-to-nearest-even
__device__ __forceinline__ u16 f2bf(float f) {
    union { float f; unsigned u; } v; v.f = f;
    unsigned r = v.u + 0x7fffu + ((v.u >> 16) & 1u);
    return (u16)(r >> 16);
}

// Barrier that drains ONLY lgkm (LDS). Cross-wave LDS data is produced by
// ds_write from registers, so lgkmcnt(0) is the full producer-side
// requirement; global prefetch loads stay in flight (consumer-waited at use).
__device__ __forceinline__ void wg_barrier() {
    asm volatile("s_waitcnt lgkmcnt(0)" ::: "memory");
    __builtin_amdgcn_s_barrier();
}

// (256,3): cap ~168 VGPR/wave. KT=32 demand ~125-140 (KT=64 was ~170 -> r2's
// spill disaster). 3 blocks/CU -> 12 waves/CU.
template<int KSPLIT>
__global__ __launch_bounds__(256, 3)
void sdpa_fwd(const float* __restrict__ Q, const float* __restrict__ K,
              const float* __restrict__ V, const int* __restrict__ M,
              const float* __restrict__ W, float* __restrict__ O,
              float* __restrict__ OP, float* __restrict__ MP,
              float* __restrict__ LP)
{
    const int b     = blockIdx.x & 7;               // batch -> XCD-local K/V reuse
    const int qbase = ((blockIdx.x >> 3) & 31) * QT;
    const int split = blockIdx.x >> 8;
    const int ntq   = NT / KSPLIT, ntr = NT % KSPLIT;
    const int kt0   = split * ntq + (split < ntr ? split : ntr);
    const int nts   = ntq + (split < ntr ? 1 : 0);

    // Ss aliases Ks (Ks dead after QK reads; mid barrier protects overlap).
    __shared__ u16 Ks[KT][D_ + 8];   // 8704 B, K tile [k][d]
    __shared__ u16 Vt[D_][KT + 8];   // 10240 B, V tile transposed [d][k]
    u16 (*Ss)[KT + 8] = (u16 (*)[KT + 8])&Ks[0][0];  // 5120 B <= Ks

    const int tid  = threadIdx.x;
    const int wv   = tid >> 6;
    const int lane = tid & 63;
    const int quad = lane >> 4;
    const int lq   = lane & 15;
    const int c4s  = (tid & 31) * 4;   // staging d-offset
    const int k4   = (tid >> 5) * 4;   // staging k-row base (0..28)

    // ---- persistent Q A-fragments (wave rows wv*16 + lq), direct from global ----
    bf16x8 qf[4];
    {
        const float* qp = Q + ((size_t)b * NQ_ + qbase + wv * 16 + lq) * D_;
        #pragma unroll
        for (int t = 0; t < 4; ++t) {
            float4 a0 = *(const float4*)(qp + t * 32 + quad * 8);
            float4 a1 = *(const float4*)(qp + t * 32 + quad * 8 + 4);
            qf[t][0] = (short)f2bf(a0.x); qf[t][1] = (short)f2bf(a0.y);
            qf[t][2] = (short)f2bf(a0.z); qf[t][3] = (short)f2bf(a0.w);
            qf[t][4] = (short)f2bf(a1.x); qf[t][5] = (short)f2bf(a1.y);
            qf[t][6] = (short)f2bf(a1.z); qf[t][7] = (short)f2bf(a1.w);
        }
    }

    // online-softmax state in log2 domain; row = quad*4 + r of wave's 16 rows
    float m2[4], l[4];
    #pragma unroll
    for (int r = 0; r < 4; ++r) { m2[r] = -INFINITY; l[r] = 0.f; }
    f32x4 o[8];
    #pragma unroll
    for (int c = 0; c < 8; ++c) o[c] = (f32x4){0.f, 0.f, 0.f, 0.f};

    const float SCL = 0.08838834764831845f * 1.44269504088896f; // 1/sqrt(128)*log2e

    // W/mask prefetch registers (one tile ahead). Mask is int32.
    float    wr[4][2];
    unsigned mpack[4];
    const float* wp  = W + ((size_t)b * NQ_ + qbase + wv * 16 + quad * 4) * SK_ + lq;
    const int*   mp_ = M + ((size_t)b * NQ_ + qbase + wv * 16 + quad * 4) * SK_ + lq;
    auto load_wm = [&](int kb_el) {
        #pragma unroll
        for (int r = 0; r < 4; ++r) {
            unsigned mp = 0;
            #pragma unroll
            for (int c = 0; c < 2; ++c) {
                size_t idx = (size_t)r * SK_ + kb_el + c * 16;
                wr[r][c] = wp[idx];
                mp |= (mp_[idx] != 0 ? 1u : 0u) << c;
            }
            mpack[r] = mp;
        }
    };

    // K/V tile prefetch registers (one tile ahead)
    float4 kr[4], vr[4];
    auto load_kv = [&](int kb_el) {
        const float* kp = K + ((size_t)b * SK_ + kb_el) * D_ + c4s;
        const float* vp = V + ((size_t)b * SK_ + kb_el) * D_ + c4s;
        #pragma unroll
        for (int i = 0; i < 4; ++i) {
            kr[i] = *(const float4*)(kp + (size_t)(k4 + i) * D_);
            vr[i] = *(const float4*)(vp + (size_t)(k4 + i) * D_);
        }
    };

    load_kv(kt0 * KT);
    load_wm(kt0 * KT);

    #pragma unroll 1
    for (int kt = 0; kt < nts; ++kt) {
        const int gt = kt0 + kt;
        // ---- stage prefetched K/V regs -> LDS (bf16; V transposed) ----
        #pragma unroll
        for (int i = 0; i < 4; ++i) {
            float4 kv = kr[i];
            *(ushort4*)&Ks[k4 + i][c4s] =
                make_ushort4(f2bf(kv.x), f2bf(kv.y), f2bf(kv.z), f2bf(kv.w));
        }
        {
            float4 v0 = vr[0], v1 = vr[1], v2 = vr[2], v3 = vr[3];
            // known ~16-way bank conflict on these writes; next-round target
            *(ushort4*)&Vt[c4s + 0][k4] = make_ushort4(f2bf(v0.x), f2bf(v1.x), f2bf(v2.x), f2bf(v3.x));
            *(ushort4*)&Vt[c4s + 1][k4] = make_ushort4(f2bf(v0.y), f2bf(v1.y), f2bf(v2.y), f2bf(v3.y));
            *(ushort4*)&Vt[c4s + 2][k4] = make_ushort4(f2bf(v0.z), f2bf(v1.z), f2bf(v2.z), f2bf(v3.z));
            *(ushort4*)&Vt[c4s + 3][k4] = make_ushort4(f2bf(v0.w), f2bf(v1.w), f2bf(v2.w), f2bf(v3.w));
        }
        if (kt + 1 < nts) load_kv((gt + 1) * KT);   // stays in flight across barriers
        wg_barrier();                               // stage visible to all waves

        // ---- S = Q Kt^T  (wave's 16 rows x 32 cols) ----
        f32x4 s[2];
        #pragma unroll
        for (int c = 0; c < 2; ++c) s[c] = (f32x4){0.f, 0.f, 0.f, 0.f};
        #pragma unroll
        for (int t = 0; t < 4; ++t) {
            #pragma unroll
            for (int c = 0; c < 2; ++c) {
                bf16x8 kf = *(const bf16x8*)&Ks[c * 16 + lq][t * 32 + quad * 8];
                s[c] = __builtin_amdgcn_mfma_f32_16x16x32_bf16(qf[t], kf, s[c], 0, 0, 0);
            }
        }

        // ---- logits IN PLACE (log2 domain): s = s*scale*w, mask -> -inf ----
        #pragma unroll
        for (int r = 0; r < 4; ++r)
            #pragma unroll
            for (int c = 0; c < 2; ++c) {
                float val = s[c][r] * (SCL * wr[r][c]);
                s[c][r] = ((mpack[r] >> c) & 1u) ? -INFINITY : val;
            }
        if (kt + 1 < nts) load_wm((gt + 1) * KT);   // prefetch next tile's W/mask

        wg_barrier();   // all waves done reading Ks -> Ss may overwrite it

        // ---- online softmax (P stored to Ss inside the exp loop) ----
        float alpha[4];
        #pragma unroll
        for (int r = 0; r < 4; ++r) {
            float tm = fmaxf(s[0][r], s[1][r]);
            tm = fmaxf(tm, __shfl_xor(tm, 1));
            tm = fmaxf(tm, __shfl_xor(tm, 2));
            tm = fmaxf(tm, __shfl_xor(tm, 4));
            tm = fmaxf(tm, __shfl_xor(tm, 8));
            float mn = fmaxf(m2[r], tm);
            float ms = (mn == -INFINITY) ? 0.f : mn;   // all-masked guard
            alpha[r] = exp2f(m2[r] - ms);
            float rs = 0.f;
            #pragma unroll
            for (int c = 0; c < 2; ++c) {
                float pv = exp2f(s[c][r] - ms);
                rs += pv;
                Ss[wv * 16 + quad * 4 + r][c * 16 + lq] = f2bf(pv);
            }
            rs += __shfl_xor(rs, 1);
            rs += __shfl_xor(rs, 2);
            rs += __shfl_xor(rs, 4);
            rs += __shfl_xor(rs, 8);
            l[r]  = l[r] * alpha[r] + rs;
            m2[r] = mn;
        }
        #pragma unroll
        for (int c = 0; c < 8; ++c)
            #pragma unroll
            for (int r = 0; r < 4; ++r)
                o[c][r] *= alpha[r];

        // ---- O += P Vt  (same-wave LDS RAW on Ss is in-order, no barrier) ----
        {
            bf16x8 af = *(const bf16x8*)&Ss[wv * 16 + lq][quad * 8];
            #pragma unroll
            for (int c = 0; c < 8; ++c) {
                bf16x8 vf = *(const bf16x8*)&Vt[c * 16 + lq][quad * 8];
                o[c] = __builtin_amdgcn_mfma_f32_16x16x32_bf16(af, vf, o[c], 0, 0, 0);
            }
        }
        wg_barrier();   // protect Ks(Ss)/Vt before next stage
    }

    // ---- epilogue ----
    if (KSPLIT == 1) {
        #pragma unroll
        for (int r = 0; r < 4; ++r) {
            float li = 1.0f / l[r];
            float* op = O + ((size_t)b * NQ_ + qbase + wv * 16 + quad * 4 + r) * D_;
            #pragma unroll
            for (int c = 0; c < 8; ++c)
                op[c * 16 + lq] = o[c][r] * li;
        }
    } else {
        // unnormalized partial O + per-row (m, l) in log2 domain
        const size_t base = ((size_t)split * B_ + b) * NQ_ + qbase + wv * 16 + quad * 4;
        #pragma unroll
        for (int r = 0; r < 4; ++r) {
            float* op = OP + (base + r) * (size_t)D_;
            #pragma unroll
            for (int c = 0; c < 8; ++c)
                op[c * 16 + lq] = o[c][r];
            if (lq == 0) { MP[base + r] = m2[r]; LP[base + r] = l[r]; }
        }
    }
}

template<int KSPLIT>
__global__ __launch_bounds__(256)
void sdpa_merge(const float* __restrict__ OP, const float* __restrict__ MP,
                const float* __restrict__ LP, float* __restrict__ O)
{
    const int idx = blockIdx.x * 256 + threadIdx.x;   // over B*NQ*D/4
    const int row = idx >> 5;                         // D/4 = 32 float4 per row
    const int d4  = (idx & 31) * 4;
    constexpr size_t RN = (size_t)B_ * NQ_;

    float mr[KSPLIT];
    float m = -INFINITY;
    #pragma unroll
    for (int s = 0; s < KSPLIT; ++s) {
        mr[s] = MP[s * RN + row];
        m = fmaxf(m, mr[s]);
    }
    const float ms = (m == -INFINITY) ? 0.f : m;
    float L = 0.f;
    float4 acc = make_float4(0.f, 0.f, 0.f, 0.f);
    #pragma unroll
    for (int s = 0; s < KSPLIT; ++s) {
        const float a = exp2f(mr[s] - ms);            // exp2(-inf) = 0 for dead splits
        L += a * LP[s * RN + row];
        const float4 v = *(const float4*)(OP + (s * RN + row) * D_ + d4);
        acc.x += a * v.x; acc.y += a * v.y; acc.z += a * v.z; acc.w += a * v.w;
    }
    const float inv = 1.f / L;
    *(float4*)(O + (size_t)row * D_ + d4) =
        make_float4(acc.x * inv, acc.y * inv, acc.z * inv, acc.w * inv);
}

extern "C" void kernel_launch(void* const* d_in, const int* in_sizes, int n_in,
                              void* d_out, int out_size, void* d_ws, size_t ws_size,
                              hipStream_t stream) {
    const float* Q = (const float*)d_in[0];
    const float* K = (const float*)d_in[1];
    const float* V = (const float*)d_in[2];
    const int*   M = (const int*)d_in[3];    // bool mask uploaded as int32
    const float* W = (const float*)d_in[4];
    float*       O = (float*)d_out;

    const size_t RN = (size_t)B_ * NQ_;
    // per split: OP (RN*D f32) + m (RN) + l (RN), all f32
    auto need = [&](int s) { return (size_t)s * RN * (D_ + 2) * sizeof(float); };

    if (ws_size >= need(3)) {
        // 768 blocks = exactly 3 blocks/CU resident -> 12 waves/CU
        float* OP = (float*)d_ws;
        float* MP = OP + 3 * RN * D_;
        float* LP = MP + 3 * RN;
        sdpa_fwd<3><<<dim3(256 * 3), 256, 0, stream>>>(Q, K, V, M, W, O, OP, MP, LP);
        sdpa_merge<3><<<dim3((unsigned)(RN * D_ / 4 / 256)), 256, 0, stream>>>(OP, MP, LP, O);
    } else if (ws_size >= need(2)) {
        float* OP = (float*)d_ws;
        float* MP = OP + 2 * RN * D_;
        float* LP = MP + 2 * RN;
        sdpa_fwd<2><<<dim3(256 * 2), 256, 0, stream>>>(Q, K, V, M, W, O, OP, MP, LP);
        sdpa_merge<2><<<dim3((unsigned)(RN * D_ / 4 / 256)), 256, 0, stream>>>(OP, MP, LP, O);
    } else {
        sdpa_fwd<1><<<dim3(256), 256, 0, stream>>>(Q, K, V, M, W, O,
                                                   nullptr, nullptr, nullptr);
    }
}